// Round 1
// baseline (533.774 us; speedup 1.0000x reference)
//
#include <hip/hip_runtime.h>

// Problem constants
// B=32, C=273, T=4096, CHOUT=270, D=242 (11x11 freqs x {cos,sin})
#define NB 32
#define NC 273
#define NT 4096
#define NO 270
#define ND 242

typedef __attribute__((ext_vector_type(8))) short short8;
typedef __attribute__((ext_vector_type(4))) float f32x4;

__device__ __forceinline__ short f2bf(float f) {
    union { float f; unsigned int u; } x;
    x.f = f;
    unsigned int r = x.u + 0x7fffu + ((x.u >> 16) & 1u);  // RNE (no NaN/inf in data)
    return (short)(r >> 16);
}

// ---------------------------------------------------------------------------
// Kernel 1: Fourier embedding. emb[b*273+c][242]: cos at [idx], sin at [121+idx]
// ---------------------------------------------------------------------------
__global__ void emb_kernel(const float* __restrict__ pos, float* __restrict__ emb) {
    const int g = blockIdx.x * 256 + threadIdx.x;
    const int TOT = NB * NC * 121;  // 1,057,056
    if (g >= TOT) return;
    const int p = g / 121;
    const int idx = g - p * 121;
    const int fi = idx / 11;
    const int fj = idx - fi * 11;
    const float scale = 4.487989505128276f;  // 2*pi/1.4
    const float px = pos[p * 2] + 0.2f;
    const float py = pos[p * 2 + 1] + 0.2f;
    const float loc = px * (scale * (float)fi) + py * (scale * (float)fj);
    emb[(size_t)p * ND + idx] = cosf(loc);
    emb[(size_t)p * ND + 121 + idx] = sinf(loc);
}

// ---------------------------------------------------------------------------
// Kernel 2: scores[b][o][c] = sum_d heads[subj[b]][o][d]*emb[b][c][d] + offset
// fp32 tiled GEMM, 64x64 tile, Kchunk=16, K stored transposed in LDS so the
// inner loop is two float4 LDS reads + 16 fmac.
// ---------------------------------------------------------------------------
__global__ __launch_bounds__(256) void scores_kernel(
    const float* __restrict__ emb, const float* __restrict__ heads,
    const int* __restrict__ subj, const float* __restrict__ pos,
    float* __restrict__ scores) {
    __shared__ float As[16 * 68];  // As[k][i] = heads[s][o0+i][kc+k]
    __shared__ float Bs[16 * 68];  // Bs[k][j] = emb[b][c0+j][kc+k]
    const int b = blockIdx.z;
    const int o0 = blockIdx.y * 64;
    const int c0 = blockIdx.x * 64;
    const int tid = threadIdx.x;
    const int s = subj[b];
    const int tx = tid & 15, ty = tid >> 4;
    const int li = tid & 63;   // staging row within tile
    const int kq = tid >> 6;   // 0..3 -> covers k = kq*4 .. kq*4+3

    float acc[4][4] = {};

    const int o_st = o0 + li;
    const int c_st = c0 + li;
    const size_t hb = ((size_t)(s * NO + o_st)) * ND;
    const size_t eb = ((size_t)(b * NC + c_st)) * ND;
    const bool ovalid = (o_st < NO);
    const bool cvalid = (c_st < NC);

    for (int kc = 0; kc < 256; kc += 16) {
#pragma unroll
        for (int kk = 0; kk < 4; ++kk) {
            const int k = kq * 4 + kk;
            const int d = kc + k;
            As[k * 68 + li] = (ovalid && d < ND) ? heads[hb + d] : 0.0f;
            Bs[k * 68 + li] = (cvalid && d < ND) ? emb[eb + d] : 0.0f;
        }
        __syncthreads();
#pragma unroll
        for (int k = 0; k < 16; ++k) {
            const float4 a = *reinterpret_cast<const float4*>(&As[k * 68 + ty * 4]);
            const float4 bv = *reinterpret_cast<const float4*>(&Bs[k * 68 + tx * 4]);
            const float aa[4] = {a.x, a.y, a.z, a.w};
            const float bb[4] = {bv.x, bv.y, bv.z, bv.w};
#pragma unroll
            for (int ii = 0; ii < 4; ++ii)
#pragma unroll
                for (int jj = 0; jj < 4; ++jj) acc[ii][jj] += aa[ii] * bb[jj];
        }
        __syncthreads();
    }

#pragma unroll
    for (int ii = 0; ii < 4; ++ii) {
        const int o = o0 + ty * 4 + ii;
        if (o >= NO) continue;
#pragma unroll
        for (int jj = 0; jj < 4; ++jj) {
            const int c = c0 + tx * 4 + jj;
            if (c >= NC) continue;
            const float px = pos[((size_t)(b * NC + c)) * 2];
            const float py = pos[((size_t)(b * NC + c)) * 2 + 1];
            const float off = (px == -0.1f && py == -0.1f) ? -1e9f : 0.0f;
            scores[((size_t)(b * NO + o)) * NC + c] = acc[ii][jj] + off;
        }
    }
}

// ---------------------------------------------------------------------------
// Kernel 3: softmax over channels (273), in place. One wave per (b,o) row.
// ---------------------------------------------------------------------------
__global__ __launch_bounds__(64) void softmax_kernel(float* __restrict__ scores) {
    const int row = blockIdx.x;  // b*270 + o
    float* s = scores + (size_t)row * NC;
    const int lane = threadIdx.x;

    float v[5];
    int cnt = 0;
    float mx = -1e30f;
    for (int c = lane; c < NC; c += 64) {
        v[cnt] = s[c];
        mx = fmaxf(mx, v[cnt]);
        ++cnt;
    }
#pragma unroll
    for (int off = 32; off; off >>= 1) mx = fmaxf(mx, __shfl_xor(mx, off));
    float sum = 0.0f;
    for (int i = 0; i < cnt; ++i) {
        v[i] = expf(v[i] - mx);
        sum += v[i];
    }
#pragma unroll
    for (int off = 32; off; off >>= 1) sum += __shfl_xor(sum, off);
    const float inv = 1.0f / sum;
    int i = 0;
    for (int c = lane; c < NC; c += 64) { s[c] = v[i++] * inv; }
}

// ---------------------------------------------------------------------------
// Kernel 4: out[b][o][t] = sum_c w[b][o][c] * meg[b][c][t]
// bf16 MFMA 16x16x32. Block tile: M=64 (o), N=128 (t), K chunks of 32 (c).
// A (weights) staged ONCE per block in fragment-linear bf16 LDS
//   (lane l of frag (ch,mt) holds W[o0+mt*16+(l&15)][ch*32+(l>>4)*8+j], j=0..7)
// B (meg) staged fp32 per chunk, frag gathered with strided b32 reads + cvt.
// ---------------------------------------------------------------------------
__global__ __launch_bounds__(256) void einsum_kernel(
    const float* __restrict__ meg, const float* __restrict__ wts,
    float* __restrict__ out) {
    __shared__ short Alds[9 * 4 * 64 * 8];  // 36864 B
    __shared__ float Blds[32 * 132];        // 16896 B
    const int b = blockIdx.z;
    const int o0 = blockIdx.y * 64;
    const int t0 = blockIdx.x * 128;
    const int tid = threadIdx.x;
    const int l = tid & 63;
    const int wv = tid >> 6;  // wave id 0..3
    const int q = l >> 4;     // 0..3
    const int nlo = l & 15;

    // ---- Stage A: weights tile [64 o x 288 c] -> bf16 fragment-linear ----
    {
        const int mt = wv;
        const int o = o0 + mt * 16 + nlo;
        const bool ov = (o < NO);
        const float* wrow = wts + ((size_t)(b * NO + o)) * NC;
        for (int ch = 0; ch < 9; ++ch) {
            const int k0 = ch * 32 + q * 8;
            short8 v;
#pragma unroll
            for (int j = 0; j < 8; ++j) {
                const int c = k0 + j;
                v[j] = f2bf((ov && c < NC) ? wrow[c] : 0.0f);
            }
            *reinterpret_cast<short8*>(&Alds[((ch * 4 + mt) * 64 + l) * 8]) = v;
        }
    }
    __syncthreads();

    f32x4 acc[4][2];
#pragma unroll
    for (int i = 0; i < 4; ++i)
#pragma unroll
        for (int j = 0; j < 2; ++j) acc[i][j] = {0.f, 0.f, 0.f, 0.f};

    for (int ch = 0; ch < 9; ++ch) {
        const int kc = ch * 32;
        // stage B chunk: meg[kc..kc+31][t0..t0+127] fp32 -> Blds[32][132]
        {
            const int tcol = (tid & 31) * 4;
            const int r0 = tid >> 5;  // 0..7
#pragma unroll
            for (int p = 0; p < 4; ++p) {
                const int cl = r0 + p * 8;  // 0..31
                const int c = kc + cl;
                float4 v = make_float4(0.f, 0.f, 0.f, 0.f);
                if (c < NC)
                    v = *reinterpret_cast<const float4*>(
                        &meg[((size_t)(b * NC + c)) * NT + t0 + tcol]);
                *reinterpret_cast<float4*>(&Blds[cl * 132 + tcol]) = v;
            }
        }
        __syncthreads();

        short8 bfr[2];
#pragma unroll
        for (int nf = 0; nf < 2; ++nf) {
            const int n = wv * 32 + nf * 16 + nlo;
            short8 v;
#pragma unroll
            for (int j = 0; j < 8; ++j) v[j] = f2bf(Blds[(q * 8 + j) * 132 + n]);
            bfr[nf] = v;
        }
#pragma unroll
        for (int mt = 0; mt < 4; ++mt) {
            const short8 av =
                *reinterpret_cast<const short8*>(&Alds[((ch * 4 + mt) * 64 + l) * 8]);
            acc[mt][0] = __builtin_amdgcn_mfma_f32_16x16x32_bf16(av, bfr[0], acc[mt][0], 0, 0, 0);
            acc[mt][1] = __builtin_amdgcn_mfma_f32_16x16x32_bf16(av, bfr[1], acc[mt][1], 0, 0, 0);
        }
        __syncthreads();
    }

    // ---- epilogue: C/D layout col = l&15, row = (l>>4)*4 + reg ----
#pragma unroll
    for (int mt = 0; mt < 4; ++mt) {
        const int obase = o0 + mt * 16 + q * 4;
#pragma unroll
        for (int nf = 0; nf < 2; ++nf) {
            const int t = t0 + wv * 32 + nf * 16 + nlo;
#pragma unroll
            for (int r = 0; r < 4; ++r) {
                const int o = obase + r;
                if (o < NO)
                    out[((size_t)(b * NO + o)) * NT + t] = acc[mt][nf][r];
            }
        }
    }
}

// ---------------------------------------------------------------------------
extern "C" void kernel_launch(void* const* d_in, const int* in_sizes, int n_in,
                              void* d_out, int out_size, void* d_ws, size_t ws_size,
                              hipStream_t stream) {
    const float* meg = (const float*)d_in[0];       // [32,273,4096] f32
    const float* pos = (const float*)d_in[1];       // [32,273,2] f32
    const int* subj = (const int*)d_in[2];          // [32] i32
    const float* heads = (const float*)d_in[3];     // [200,270,242] f32
    float* out = (float*)d_out;                     // [32,270,4096] f32

    float* emb = (float*)d_ws;                       // 32*273*242 = 2,114,112 f32
    float* scores = emb + (size_t)NB * NC * ND;      // 32*270*273 = 2,358,720 f32

    const int emb_items = NB * NC * 121;
    emb_kernel<<<dim3((emb_items + 255) / 256), dim3(256), 0, stream>>>(pos, emb);
    scores_kernel<<<dim3(5, 5, NB), dim3(256), 0, stream>>>(emb, heads, subj, pos, scores);
    softmax_kernel<<<dim3(NB * NO), dim3(64), 0, stream>>>(scores);
    einsum_kernel<<<dim3(NT / 128, 5, NB), dim3(256), 0, stream>>>(meg, scores, out);
}

// Round 2
// 450.162 us; speedup vs baseline: 1.1857x; 1.1857x over previous
//
#include <hip/hip_runtime.h>

// Problem constants
// B=32, C=273, T=4096, CHOUT=270, D=242 (11x11 freqs x {cos,sin})
#define NB 32
#define NC 273
#define NT 4096
#define NO 270
#define ND 242
#define CK 288  // padded channel count for megT (multiple of 32)

typedef __attribute__((ext_vector_type(8))) short short8;
typedef __attribute__((ext_vector_type(4))) float f32x4;

__device__ __forceinline__ short f2bf(float f) {
    union { float f; unsigned int u; } x;
    x.f = f;
    unsigned int r = x.u + 0x7fffu + ((x.u >> 16) & 1u);  // RNE (no NaN/inf in data)
    return (short)(r >> 16);
}

// ---------------------------------------------------------------------------
// Kernel 1: Fourier embedding. emb[b*273+c][242]: cos at [idx], sin at [121+idx]
// ---------------------------------------------------------------------------
__global__ void emb_kernel(const float* __restrict__ pos, float* __restrict__ emb) {
    const int g = blockIdx.x * 256 + threadIdx.x;
    const int TOT = NB * NC * 121;  // 1,057,056
    if (g >= TOT) return;
    const int p = g / 121;
    const int idx = g - p * 121;
    const int fi = idx / 11;
    const int fj = idx - fi * 11;
    const float scale = 4.487989505128276f;  // 2*pi/1.4
    const float px = pos[p * 2] + 0.2f;
    const float py = pos[p * 2 + 1] + 0.2f;
    const float loc = px * (scale * (float)fi) + py * (scale * (float)fj);
    emb[(size_t)p * ND + idx] = cosf(loc);
    emb[(size_t)p * ND + 121 + idx] = sinf(loc);
}

// ---------------------------------------------------------------------------
// Kernel 2: scores[b][o][c] = sum_d heads[subj[b]][o][d]*emb[b][c][d] + offset
// fp32 tiled GEMM, 64x64 tile, Kchunk=16. Staging: 8 lanes per row, float2
// loads (64B segments), written transposed into LDS [k][row] (+pad).
// ---------------------------------------------------------------------------
__global__ __launch_bounds__(256) void scores_kernel(
    const float* __restrict__ emb, const float* __restrict__ heads,
    const int* __restrict__ subj, const float* __restrict__ pos,
    float* __restrict__ scores) {
    __shared__ float As[16 * 68];  // As[k][i] = heads[s][o0+i][kc+k]
    __shared__ float Bs[16 * 68];  // Bs[k][j] = emb[b][c0+j][kc+k]
    const int b = blockIdx.z;
    const int o0 = blockIdx.y * 64;
    const int c0 = blockIdx.x * 64;
    const int tid = threadIdx.x;
    const int s = subj[b];
    const int tx = tid & 15, ty = tid >> 4;
    const int srow = tid >> 3;  // 0..31
    const int sfp = tid & 7;    // float2 index: cols sfp*2, sfp*2+1

    float acc[4][4] = {};

    for (int kc = 0; kc < 256; kc += 16) {
#pragma unroll
        for (int half = 0; half < 2; ++half) {
            const int row = srow + half * 32;
            const int o = o0 + row;
            const int c = c0 + row;
            const int d = kc + sfp * 2;  // even; ND even -> never a partial pair
            float2 av = make_float2(0.f, 0.f);
            float2 bv = make_float2(0.f, 0.f);
            if (d < ND) {
                if (o < NO)
                    av = *reinterpret_cast<const float2*>(
                        &heads[((size_t)(s * NO + o)) * ND + d]);
                if (c < NC)
                    bv = *reinterpret_cast<const float2*>(
                        &emb[((size_t)(b * NC + c)) * ND + d]);
            }
            As[(sfp * 2 + 0) * 68 + row] = av.x;
            As[(sfp * 2 + 1) * 68 + row] = av.y;
            Bs[(sfp * 2 + 0) * 68 + row] = bv.x;
            Bs[(sfp * 2 + 1) * 68 + row] = bv.y;
        }
        __syncthreads();
#pragma unroll
        for (int k = 0; k < 16; ++k) {
            const float4 a = *reinterpret_cast<const float4*>(&As[k * 68 + ty * 4]);
            const float4 bvv = *reinterpret_cast<const float4*>(&Bs[k * 68 + tx * 4]);
            const float aa[4] = {a.x, a.y, a.z, a.w};
            const float bb[4] = {bvv.x, bvv.y, bvv.z, bvv.w};
#pragma unroll
            for (int ii = 0; ii < 4; ++ii)
#pragma unroll
                for (int jj = 0; jj < 4; ++jj) acc[ii][jj] += aa[ii] * bb[jj];
        }
        __syncthreads();
    }

#pragma unroll
    for (int ii = 0; ii < 4; ++ii) {
        const int o = o0 + ty * 4 + ii;
        if (o >= NO) continue;
#pragma unroll
        for (int jj = 0; jj < 4; ++jj) {
            const int c = c0 + tx * 4 + jj;
            if (c >= NC) continue;
            const float px = pos[((size_t)(b * NC + c)) * 2];
            const float py = pos[((size_t)(b * NC + c)) * 2 + 1];
            const float off = (px == -0.1f && py == -0.1f) ? -1e9f : 0.0f;
            scores[((size_t)(b * NO + o)) * NC + c] = acc[ii][jj] + off;
        }
    }
}

// ---------------------------------------------------------------------------
// Kernel 3: softmax over channels (273), in place. One wave per (b,o) row.
// ---------------------------------------------------------------------------
__global__ __launch_bounds__(64) void softmax_kernel(float* __restrict__ scores) {
    const int row = blockIdx.x;  // b*270 + o
    float* s = scores + (size_t)row * NC;
    const int lane = threadIdx.x;

    float v[5];
    int cnt = 0;
    float mx = -1e30f;
    for (int c = lane; c < NC; c += 64) {
        v[cnt] = s[c];
        mx = fmaxf(mx, v[cnt]);
        ++cnt;
    }
#pragma unroll
    for (int off = 32; off; off >>= 1) mx = fmaxf(mx, __shfl_xor(mx, off));
    float sum = 0.0f;
    for (int i = 0; i < cnt; ++i) {
        v[i] = expf(v[i] - mx);
        sum += v[i];
    }
#pragma unroll
    for (int off = 32; off; off >>= 1) sum += __shfl_xor(sum, off);
    const float inv = 1.0f / sum;
    int i = 0;
    for (int c = lane; c < NC; c += 64) { s[c] = v[i++] * inv; }
}

// ---------------------------------------------------------------------------
// Kernel 4: transpose+convert meg [b][c][t] f32 -> megT [b][t][ck] bf16,
// ck in [0,288), zero-filled for c >= 273. 32x32 LDS tile.
// ---------------------------------------------------------------------------
__global__ __launch_bounds__(256) void transpose_kernel(
    const float* __restrict__ meg, short* __restrict__ megT) {
    __shared__ float lds[32 * 33];
    const int b = blockIdx.z;
    const int t0 = blockIdx.x * 32;
    const int c0 = blockIdx.y * 32;
    const int tx = threadIdx.x & 31;
    const int ty = threadIdx.x >> 5;  // 0..7
#pragma unroll
    for (int i = 0; i < 4; ++i) {
        const int c = c0 + ty + i * 8;
        float v = 0.f;
        if (c < NC) v = meg[((size_t)(b * NC + c)) * NT + t0 + tx];
        lds[tx * 33 + ty + i * 8] = v;
    }
    __syncthreads();
#pragma unroll
    for (int i = 0; i < 4; ++i) {
        const int tl = ty + i * 8;
        megT[((size_t)(b * NT + t0 + tl)) * CK + c0 + tx] = f2bf(lds[tl * 33 + tx]);
    }
}

// ---------------------------------------------------------------------------
// Kernel 5: out[b][o][t] = sum_c w[b][o][c] * megT[b][t][c]
// bf16 MFMA 16x16x32. Block tile M=64 (o), N=128 (t), K=288 in 9 chunks of 32.
// A (weights) staged once in fragment-linear bf16 LDS; B frags are direct
// 16B global loads from megT (8 contiguous bf16 k-values at fixed t).
// NO barrier inside the K-loop.
// ---------------------------------------------------------------------------
__global__ __launch_bounds__(256) void einsum_kernel(
    const short* __restrict__ megT, const float* __restrict__ wts,
    float* __restrict__ out) {
    __shared__ short Alds[9 * 4 * 64 * 8];  // 36864 B
    const int b = blockIdx.z;
    const int o0 = blockIdx.y * 64;
    const int t0 = blockIdx.x * 128;
    const int tid = threadIdx.x;
    const int l = tid & 63;
    const int wv = tid >> 6;  // wave id 0..3 -> n-cols wv*32..wv*32+31
    const int q = l >> 4;     // 0..3
    const int nlo = l & 15;

    // ---- Stage A: weights tile [64 o x 288 c] -> bf16 fragment-linear ----
    {
        const int mt = wv;
        const int o = o0 + mt * 16 + nlo;
        const bool ov = (o < NO);
        const float* wrow = wts + ((size_t)(b * NO + (ov ? o : 0))) * NC;
        for (int ch = 0; ch < 9; ++ch) {
            const int k0 = ch * 32 + q * 8;
            short8 v;
#pragma unroll
            for (int j = 0; j < 8; ++j) {
                const int c = k0 + j;
                v[j] = f2bf((ov && c < NC) ? wrow[c] : 0.0f);
            }
            *reinterpret_cast<short8*>(&Alds[((ch * 4 + mt) * 64 + l) * 8]) = v;
        }
    }
    __syncthreads();

    f32x4 acc[4][2];
#pragma unroll
    for (int i = 0; i < 4; ++i)
#pragma unroll
        for (int j = 0; j < 2; ++j) acc[i][j] = {0.f, 0.f, 0.f, 0.f};

    // B base: lane l, frag nf covers t = t0 + wv*32 + nf*16 + nlo, k = q*8+j
    const short* bbase = megT + ((size_t)(b * NT + t0 + wv * 32 + nlo)) * CK + q * 8;

#pragma unroll
    for (int ch = 0; ch < 9; ++ch) {
        const short8 b0 = *reinterpret_cast<const short8*>(bbase + ch * 32);
        const short8 b1 = *reinterpret_cast<const short8*>(bbase + 16 * CK + ch * 32);
#pragma unroll
        for (int mt = 0; mt < 4; ++mt) {
            const short8 av =
                *reinterpret_cast<const short8*>(&Alds[((ch * 4 + mt) * 64 + l) * 8]);
            acc[mt][0] = __builtin_amdgcn_mfma_f32_16x16x32_bf16(av, b0, acc[mt][0], 0, 0, 0);
            acc[mt][1] = __builtin_amdgcn_mfma_f32_16x16x32_bf16(av, b1, acc[mt][1], 0, 0, 0);
        }
    }

    // ---- epilogue: C/D layout col = l&15, row = (l>>4)*4 + reg ----
#pragma unroll
    for (int mt = 0; mt < 4; ++mt) {
        const int obase = o0 + mt * 16 + q * 4;
#pragma unroll
        for (int nf = 0; nf < 2; ++nf) {
            const int t = t0 + wv * 32 + nf * 16 + nlo;
#pragma unroll
            for (int r = 0; r < 4; ++r) {
                const int o = obase + r;
                if (o < NO)
                    out[((size_t)(b * NO + o)) * NT + t] = acc[mt][nf][r];
            }
        }
    }
}

// ---------------------------------------------------------------------------
extern "C" void kernel_launch(void* const* d_in, const int* in_sizes, int n_in,
                              void* d_out, int out_size, void* d_ws, size_t ws_size,
                              hipStream_t stream) {
    const float* meg = (const float*)d_in[0];       // [32,273,4096] f32
    const float* pos = (const float*)d_in[1];       // [32,273,2] f32
    const int* subj = (const int*)d_in[2];          // [32] i32
    const float* heads = (const float*)d_in[3];     // [200,270,242] f32
    float* out = (float*)d_out;                     // [32,270,4096] f32

    float* emb = (float*)d_ws;                       // 32*273*242 f32   (8.5 MB)
    float* scores = emb + (size_t)NB * NC * ND;      // 32*270*273 f32   (9.4 MB)
    short* megT = (short*)(scores + (size_t)NB * NO * NC);  // 32*4096*288 bf16 (75.5 MB)

    const int emb_items = NB * NC * 121;
    emb_kernel<<<dim3((emb_items + 255) / 256), dim3(256), 0, stream>>>(pos, emb);
    scores_kernel<<<dim3(5, 5, NB), dim3(256), 0, stream>>>(emb, heads, subj, pos, scores);
    softmax_kernel<<<dim3(NB * NO), dim3(64), 0, stream>>>(scores);
    transpose_kernel<<<dim3(NT / 32, CK / 32, NB), dim3(256), 0, stream>>>(meg, megT);
    einsum_kernel<<<dim3(NT / 128, 5, NB), dim3(256), 0, stream>>>(megT, scores, out);
}

// Round 3
// 398.945 us; speedup vs baseline: 1.3380x; 1.1284x over previous
//
#include <hip/hip_runtime.h>

// Problem constants
// B=32, C=273, T=4096, CHOUT=270, D=242 (11x11 freqs x {cos,sin})
#define NB 32
#define NC 273
#define NT 4096
#define NO 270
#define ND 242
#define CK 288   // padded channel count for megT (multiple of 32)
#define TSUB 128 // einsum t-subtile
#define NSUB 4   // subtiles per block -> 512 t per block

typedef __attribute__((ext_vector_type(8))) short short8;
typedef __attribute__((ext_vector_type(4))) float f32x4;

__device__ __forceinline__ short f2bf(float f) {
    union { float f; unsigned int u; } x;
    x.f = f;
    unsigned int r = x.u + 0x7fffu + ((x.u >> 16) & 1u);  // RNE (no NaN/inf in data)
    return (short)(r >> 16);
}

// ---------------------------------------------------------------------------
// Kernel 1: Fourier embedding. emb[b*273+c][242]: cos at [idx], sin at [121+idx]
// ---------------------------------------------------------------------------
__global__ void emb_kernel(const float* __restrict__ pos, float* __restrict__ emb) {
    const int g = blockIdx.x * 256 + threadIdx.x;
    const int TOT = NB * NC * 121;  // 1,057,056
    if (g >= TOT) return;
    const int p = g / 121;
    const int idx = g - p * 121;
    const int fi = idx / 11;
    const int fj = idx - fi * 11;
    const float scale = 4.487989505128276f;  // 2*pi/1.4
    const float px = pos[p * 2] + 0.2f;
    const float py = pos[p * 2 + 1] + 0.2f;
    const float loc = px * (scale * (float)fi) + py * (scale * (float)fj);
    emb[(size_t)p * ND + idx] = cosf(loc);
    emb[(size_t)p * ND + 121 + idx] = sinf(loc);
}

// ---------------------------------------------------------------------------
// Kernel 2: scores[b][o][c] = sum_d heads[subj[b]][o][d]*emb[b][c][d] + offset
// fp32 tiled GEMM, 32x64 tile (grid 1440 = 5.6 blocks/CU, small LDS -> high
// occupancy so staging latency is hidden by TLP). Kchunk=16.
// ---------------------------------------------------------------------------
__global__ __launch_bounds__(256) void scores_kernel(
    const float* __restrict__ emb, const float* __restrict__ heads,
    const int* __restrict__ subj, const float* __restrict__ pos,
    float* __restrict__ scores) {
    __shared__ float As[16 * 36];  // As[k][i] = heads[s][o0+i][kc+k], 32 rows +4 pad
    __shared__ float Bs[16 * 68];  // Bs[k][j] = emb[b][c0+j][kc+k], 64 rows +4 pad
    const int b = blockIdx.z;
    const int o0 = blockIdx.y * 32;
    const int c0 = blockIdx.x * 64;
    const int tid = threadIdx.x;
    const int s = subj[b];
    const int tx = tid & 15, ty = tid >> 4;  // ty 0..15
    const int srow = tid >> 3;  // 0..31
    const int sfp = tid & 7;    // float2 index: cols sfp*2, sfp*2+1

    float acc[2][4] = {};

    for (int kc = 0; kc < 256; kc += 16) {
        const int d = kc + sfp * 2;  // even; ND even -> never a partial pair
        // A: 32 rows x 16 k
        {
            const int o = o0 + srow;
            float2 av = make_float2(0.f, 0.f);
            if (d < ND && o < NO)
                av = *reinterpret_cast<const float2*>(
                    &heads[((size_t)(s * NO + o)) * ND + d]);
            As[(sfp * 2 + 0) * 36 + srow] = av.x;
            As[(sfp * 2 + 1) * 36 + srow] = av.y;
        }
        // B: 64 rows x 16 k
#pragma unroll
        for (int half = 0; half < 2; ++half) {
            const int row = srow + half * 32;
            const int c = c0 + row;
            float2 bv = make_float2(0.f, 0.f);
            if (d < ND && c < NC)
                bv = *reinterpret_cast<const float2*>(
                    &emb[((size_t)(b * NC + c)) * ND + d]);
            Bs[(sfp * 2 + 0) * 68 + row] = bv.x;
            Bs[(sfp * 2 + 1) * 68 + row] = bv.y;
        }
        __syncthreads();
#pragma unroll
        for (int k = 0; k < 16; ++k) {
            const float2 a = *reinterpret_cast<const float2*>(&As[k * 36 + ty * 2]);
            const float4 bvv = *reinterpret_cast<const float4*>(&Bs[k * 68 + tx * 4]);
            const float aa[2] = {a.x, a.y};
            const float bb[4] = {bvv.x, bvv.y, bvv.z, bvv.w};
#pragma unroll
            for (int ii = 0; ii < 2; ++ii)
#pragma unroll
                for (int jj = 0; jj < 4; ++jj) acc[ii][jj] += aa[ii] * bb[jj];
        }
        __syncthreads();
    }

#pragma unroll
    for (int ii = 0; ii < 2; ++ii) {
        const int o = o0 + ty * 2 + ii;
        if (o >= NO) continue;
#pragma unroll
        for (int jj = 0; jj < 4; ++jj) {
            const int c = c0 + tx * 4 + jj;
            if (c >= NC) continue;
            const float px = pos[((size_t)(b * NC + c)) * 2];
            const float py = pos[((size_t)(b * NC + c)) * 2 + 1];
            const float off = (px == -0.1f && py == -0.1f) ? -1e9f : 0.0f;
            scores[((size_t)(b * NO + o)) * NC + c] = acc[ii][jj] + off;
        }
    }
}

// ---------------------------------------------------------------------------
// Kernel 3: softmax over channels (273), in place. One wave per (b,o) row.
// ---------------------------------------------------------------------------
__global__ __launch_bounds__(64) void softmax_kernel(float* __restrict__ scores) {
    const int row = blockIdx.x;  // b*270 + o
    float* s = scores + (size_t)row * NC;
    const int lane = threadIdx.x;

    float v[5];
    int cnt = 0;
    float mx = -1e30f;
    for (int c = lane; c < NC; c += 64) {
        v[cnt] = s[c];
        mx = fmaxf(mx, v[cnt]);
        ++cnt;
    }
#pragma unroll
    for (int off = 32; off; off >>= 1) mx = fmaxf(mx, __shfl_xor(mx, off));
    float sum = 0.0f;
    for (int i = 0; i < cnt; ++i) {
        v[i] = expf(v[i] - mx);
        sum += v[i];
    }
#pragma unroll
    for (int off = 32; off; off >>= 1) sum += __shfl_xor(sum, off);
    const float inv = 1.0f / sum;
    int i = 0;
    for (int c = lane; c < NC; c += 64) { s[c] = v[i++] * inv; }
}

// ---------------------------------------------------------------------------
// Kernel 4: transpose+convert meg [b][c][t] f32 -> megT [b][t][ck] bf16.
// Tile 32t x 64c so each write instruction covers a full 128 B per t-row
// (32 lanes x short2) - avoids partial-line RMW on the store path.
// ---------------------------------------------------------------------------
__global__ __launch_bounds__(256) void transpose_kernel(
    const float* __restrict__ meg, short* __restrict__ megT) {
    __shared__ float lds[32 * 66];  // [t][c], +2 pad
    const int b = blockIdx.z;
    const int t0 = blockIdx.x * 32;
    const int c0 = blockIdx.y * 64;
    const int tx = threadIdx.x & 31;   // t lane for loads
    const int ty = threadIdx.x >> 5;   // 0..7
#pragma unroll
    for (int i = 0; i < 8; ++i) {
        const int cl = ty + i * 8;     // 0..63
        const int c = c0 + cl;
        float v = 0.f;
        if (c < NC) v = meg[((size_t)(b * NC + c)) * NT + t0 + tx];
        lds[tx * 66 + cl] = v;
    }
    __syncthreads();
    const int wx = threadIdx.x & 31;   // c-pair lane for stores
    const int wy = threadIdx.x >> 5;   // 0..7
    const int c = c0 + wx * 2;
    if (c < CK) {
#pragma unroll
        for (int i = 0; i < 4; ++i) {
            const int tl = wy + i * 8;  // 0..31
            short2 v;
            v.x = f2bf(lds[tl * 66 + wx * 2]);
            v.y = f2bf(lds[tl * 66 + wx * 2 + 1]);
            *reinterpret_cast<short2*>(
                &megT[((size_t)(b * NT + t0 + tl)) * CK + c]) = v;
        }
    }
}

// ---------------------------------------------------------------------------
// Kernel 5: out[b][o][t] = sum_c w[b][o][c] * megT[b][t][c]
// bf16 MFMA 16x16x32. Block: M=64 (o) x 512 t (4 subtiles of 128), K=288.
// A staged once in fragment-linear LDS. B: 36-iteration unrolled chunk stream
// with depth-3 rolling register buffer (6 x 16B loads in flight per wave).
// Stores interleave at subtile boundaries. No barrier in the K-loop.
// ---------------------------------------------------------------------------
__global__ __launch_bounds__(256) void einsum_kernel(
    const short* __restrict__ megT, const float* __restrict__ wts,
    float* __restrict__ out) {
    __shared__ short Alds[9 * 4 * 64 * 8];  // 36864 B
    const int b = blockIdx.z;
    const int o0 = blockIdx.y * 64;
    const int t0 = blockIdx.x * (TSUB * NSUB);
    const int tid = threadIdx.x;
    const int l = tid & 63;
    const int wv = tid >> 6;  // wave id 0..3 -> t-cols wv*32..wv*32+31 in subtile
    const int q = l >> 4;     // 0..3
    const int nlo = l & 15;

    // ---- Stage A: weights tile [64 o x 288 c] -> bf16 fragment-linear ----
    {
        const int mt = wv;
        const int o = o0 + mt * 16 + nlo;
        const bool ov = (o < NO);
        const float* wrow = wts + ((size_t)(b * NO + (ov ? o : 0))) * NC;
        for (int ch = 0; ch < 9; ++ch) {
            const int k0 = ch * 32 + q * 8;
            short8 v;
#pragma unroll
            for (int j = 0; j < 8; ++j) {
                const int c = k0 + j;
                v[j] = f2bf((ov && c < NC) ? wrow[c] : 0.0f);
            }
            *reinterpret_cast<short8*>(&Alds[((ch * 4 + mt) * 64 + l) * 8]) = v;
        }
    }
    __syncthreads();

    f32x4 acc[4][2];
#pragma unroll
    for (int i = 0; i < 4; ++i)
#pragma unroll
        for (int j = 0; j < 2; ++j) acc[i][j] = {0.f, 0.f, 0.f, 0.f};

    // lane l, frag nf covers t = t0 + st*128 + wv*32 + nf*16 + nlo, k = q*8+j
    const short* bbase = megT + ((size_t)(b * NT) + t0 + wv * 32 + nlo) * CK + q * 8;

    short8 Bq[3][2];
#pragma unroll
    for (int g = 0; g < 3; ++g) {  // prologue: chunks 0..2 of subtile 0
        Bq[g][0] = *reinterpret_cast<const short8*>(bbase + g * 32);
        Bq[g][1] = *reinterpret_cast<const short8*>(bbase + 16 * CK + g * 32);
    }

#pragma unroll
    for (int g = 0; g < 9 * NSUB; ++g) {
        const int st = g / 9;
        const int ch = g % 9;
        const int slot = g % 3;
#pragma unroll
        for (int mt = 0; mt < 4; ++mt) {
            const short8 av =
                *reinterpret_cast<const short8*>(&Alds[((ch * 4 + mt) * 64 + l) * 8]);
            acc[mt][0] = __builtin_amdgcn_mfma_f32_16x16x32_bf16(av, Bq[slot][0], acc[mt][0], 0, 0, 0);
            acc[mt][1] = __builtin_amdgcn_mfma_f32_16x16x32_bf16(av, Bq[slot][1], acc[mt][1], 0, 0, 0);
        }
        // refill this slot with chunk g+3 (static under full unroll)
        if (g + 3 < 9 * NSUB) {
            const int g2 = g + 3;
            const size_t off = (size_t)((g2 / 9) * TSUB) * CK + (g2 % 9) * 32;
            Bq[slot][0] = *reinterpret_cast<const short8*>(bbase + off);
            Bq[slot][1] = *reinterpret_cast<const short8*>(bbase + off + 16 * CK);
        }
        if (ch == 8) {
            // ---- store subtile st: C/D layout col = l&15, row = q*4 + reg ----
#pragma unroll
            for (int mt = 0; mt < 4; ++mt) {
                const int obase = o0 + mt * 16 + q * 4;
#pragma unroll
                for (int nf = 0; nf < 2; ++nf) {
                    const int t = t0 + st * TSUB + wv * 32 + nf * 16 + nlo;
#pragma unroll
                    for (int r = 0; r < 4; ++r) {
                        const int o = obase + r;
                        if (o < NO)
                            out[((size_t)(b * NO + o)) * NT + t] = acc[mt][nf][r];
                    }
                    acc[mt][nf] = {0.f, 0.f, 0.f, 0.f};
                }
            }
        }
    }
}

// ---------------------------------------------------------------------------
extern "C" void kernel_launch(void* const* d_in, const int* in_sizes, int n_in,
                              void* d_out, int out_size, void* d_ws, size_t ws_size,
                              hipStream_t stream) {
    const float* meg = (const float*)d_in[0];       // [32,273,4096] f32
    const float* pos = (const float*)d_in[1];       // [32,273,2] f32
    const int* subj = (const int*)d_in[2];          // [32] i32
    const float* heads = (const float*)d_in[3];     // [200,270,242] f32
    float* out = (float*)d_out;                     // [32,270,4096] f32

    float* emb = (float*)d_ws;                       // 32*273*242 f32   (8.5 MB)
    float* scores = emb + (size_t)NB * NC * ND;      // 32*270*273 f32   (9.4 MB)
    short* megT = (short*)(scores + (size_t)NB * NO * NC);  // 32*4096*288 bf16 (75.5 MB)

    const int emb_items = NB * NC * 121;
    emb_kernel<<<dim3((emb_items + 255) / 256), dim3(256), 0, stream>>>(pos, emb);
    scores_kernel<<<dim3(5, 9, NB), dim3(256), 0, stream>>>(emb, heads, subj, pos, scores);
    softmax_kernel<<<dim3(NB * NO), dim3(64), 0, stream>>>(scores);
    transpose_kernel<<<dim3(NT / 32, 5, NB), dim3(256), 0, stream>>>(meg, megT);
    einsum_kernel<<<dim3(NT / (TSUB * NSUB), 5, NB), dim3(256), 0, stream>>>(megT, scores, out);
}